// Round 13
// baseline (1012.256 us; speedup 1.0000x reference)
//
#include <hip/hip_runtime.h>
#include <math.h>

#define N_  1536
#define M_  768
#define D_  256
#define HEADS_ 8
#define DH_ 32
#define LAYERS_ 6
#define S_  2304
#define SW_ (S_/32)   // 72 mask words per row
#define NSPLIT_ 4
#define SPLEN_ (S_/NSPLIT_)   // 576 keys per split, 9 tiles of 64

typedef __attribute__((ext_vector_type(8))) short  s16x8;
typedef __attribute__((ext_vector_type(8))) __bf16 bf16x8;
typedef __attribute__((ext_vector_type(4))) float  f32x4;

static __device__ __forceinline__ f32x4 mfma16(s16x8 a, s16x8 b, f32x4 c) {
    return __builtin_amdgcn_mfma_f32_16x16x32_bf16(
        __builtin_bit_cast(bf16x8, a), __builtin_bit_cast(bf16x8, b), c, 0, 0, 0);
}

static __device__ __forceinline__ short f2bf(float f) {
    unsigned u = __builtin_bit_cast(unsigned, f);
    unsigned r = u + 0x7FFFu + ((u >> 16) & 1u);   // RNE to bf16
    return (short)(r >> 16);
}
static __device__ __forceinline__ float bf2f(short s) {
    unsigned u = ((unsigned)(unsigned short)s) << 16;
    return __builtin_bit_cast(float, u);
}
static __device__ __forceinline__ void splitf(float f, short& h, short& l) {
    h = f2bf(f);
    l = f2bf(f - bf2f(h));
}

// ---------------- prep kernels ----------------

__global__ __launch_bounds__(256) void k_absr(const float* __restrict__ r, float* __restrict__ nodes) {
    int i = blockIdx.x * 256 + threadIdx.x;
    if (i < N_) nodes[i] = fabsf(r[i]);
}

__global__ __launch_bounds__(256) void k_synd(const float* __restrict__ r, const float* __restrict__ H,
                                              float* __restrict__ nodes) {
    int row = blockIdx.x;
    int tid = threadIdx.x;
    float s = 0.f;
    for (int j = tid; j < N_; j += 256) {
        float b = (r[j] < 0.f) ? 1.f : 0.f;
        s += H[row * N_ + j] * b;
    }
    for (int o = 32; o; o >>= 1) s += __shfl_down(s, o, 64);
    __shared__ float w4[4];
    if ((tid & 63) == 0) w4[tid >> 6] = s;
    __syncthreads();
    if (tid == 0) {
        float t = w4[0] + w4[1] + w4[2] + w4[3];
        nodes[N_ + row] = fmodf(t, 2.0f);
    }
}

__global__ __launch_bounds__(256) void k_maskpack(const float* __restrict__ mask, unsigned* __restrict__ bits) {
    int w = blockIdx.x * 256 + threadIdx.x;
    if (w >= S_ * SW_) return;
    int row = w / SW_, c0 = (w % SW_) * 32;
    unsigned b = 0;
    const float* mrow = mask + (size_t)row * S_ + c0;
    for (int j = 0; j < 32; ++j)
        if (mrow[j] != 0.f) b |= (1u << j);
    bits[w] = b;
}

__global__ __launch_bounds__(256) void k_embed(const float* __restrict__ src, const float* __restrict__ tt,
                                               const int* __restrict__ tptr, const float* __restrict__ nodes,
                                               float* __restrict__ x) {
    int s = blockIdx.x, d = threadIdx.x;
    int t = tptr[0];
    x[s * D_ + d] = src[s * D_ + d] * nodes[s] * tt[t * D_ + d];
}

// ---------------- weight transpose + bf16 hi/lo split ----------------

__global__ __launch_bounds__(256) void k_wsplit(const float* __restrict__ W, short* __restrict__ oh,
                                                short* __restrict__ ol, int K, int NC,
                                                long in_ls, long out_ls) {
    __shared__ float T[32][33];
    int z = blockIdx.z;
    const float* Wz = W + (size_t)z * in_ls;
    short* ohz = oh + (size_t)z * out_ls;
    short* olz = ol + (size_t)z * out_ls;
    int n0 = blockIdx.x * 32, k0 = blockIdx.y * 32;
    int t = threadIdx.x;
    int r = t >> 3, c4 = (t & 7) * 4;
    float4 v = *(const float4*)(Wz + (size_t)(k0 + r) * NC + n0 + c4);
    T[r][c4 + 0] = v.x; T[r][c4 + 1] = v.y; T[r][c4 + 2] = v.z; T[r][c4 + 3] = v.w;
    __syncthreads();
    int n = t >> 3, k4 = (t & 7) * 4;
#pragma unroll
    for (int i = 0; i < 4; ++i) {
        float f = T[k4 + i][n];
        short hh, ll; splitf(f, hh, ll);
        ohz[(size_t)(n0 + n) * K + k0 + k4 + i] = hh;
        olz[(size_t)(n0 + n) * K + k0 + k4 + i] = ll;
    }
}

// ---------------- QKV pre-split kernels (once per layer) ----------------

__global__ __launch_bounds__(256) void k_qksplit(const float* __restrict__ qkv, short* __restrict__ qkh,
                                                 short* __restrict__ qkl) {
    int u = (blockIdx.x * 256 + threadIdx.x) * 8;
    int s = u >> 9, c = u & 511;
    const float* p = qkv + (size_t)s * 768 + c;
    float4 a = *(const float4*)p, b = *(const float4*)(p + 4);
    float v[8] = {a.x, a.y, a.z, a.w, b.x, b.y, b.z, b.w};
    s16x8 vh, vl;
#pragma unroll
    for (int i = 0; i < 8; ++i) { short hh, ll; splitf(v[i], hh, ll); vh[i] = hh; vl[i] = ll; }
    *(s16x8*)(qkh + u) = vh;
    *(s16x8*)(qkl + u) = vl;
}

__global__ __launch_bounds__(256) void k_vsplit(const float* __restrict__ qkv, short* __restrict__ vth,
                                                short* __restrict__ vtl) {
    __shared__ short Th[32][72], Tl[32][72];
    int s0 = blockIdx.x * 64, h = blockIdx.y;
    int t = threadIdx.x;
    {
        int row = t >> 2, c8 = (t & 3) * 8;
        const float* p = qkv + (size_t)(s0 + row) * 768 + 512 + h * DH_ + c8;
        float4 a = *(const float4*)p, b = *(const float4*)(p + 4);
        float v[8] = {a.x, a.y, a.z, a.w, b.x, b.y, b.z, b.w};
#pragma unroll
        for (int i = 0; i < 8; ++i) { short hh, ll; splitf(v[i], hh, ll); Th[c8 + i][row] = hh; Tl[c8 + i][row] = ll; }
    }
    __syncthreads();
    {
        int dh = t >> 3, seg = (t & 7) * 8;
        *(s16x8*)(vth + (size_t)(h * DH_ + dh) * S_ + s0 + seg) = *(s16x8*)&Th[dh][seg];
        *(s16x8*)(vtl + (size_t)(h * DH_ + dh) * S_ + s0 + seg) = *(s16x8*)&Tl[dh][seg];
    }
}

// ---------------- MFMA GEMM (unchanged) ----------------

__global__ __launch_bounds__(256) void k_mgemm(const float* __restrict__ A, const short* __restrict__ BTh,
                                               const short* __restrict__ BTl, float* __restrict__ C,
                                               int K, int NC, const float* __restrict__ bias, int relu) {
    __shared__ short Ah[32][72], Al[32][72];
    __shared__ short Bh[64][72], Bl[64][72];
    int tid = threadIdx.x;
    int w = tid >> 6, lane = tid & 63;
    int n0w = (w & 1) * 32, kh = w >> 1;
    int r0 = blockIdx.y * 32, c0 = blockIdx.x * 64;
    int g = lane >> 4, cl = lane & 15;

    f32x4 acc[2][2];
#pragma unroll
    for (int mt = 0; mt < 2; ++mt)
#pragma unroll
        for (int nt = 0; nt < 2; ++nt) acc[mt][nt] = (f32x4){0.f, 0.f, 0.f, 0.f};

    int arow = tid >> 3, akq = (tid & 7) * 8;
    int bn = tid >> 2, bkq = (tid & 3) * 16;

    for (int k0 = 0; k0 < K; k0 += 64) {
        __syncthreads();
        {
            const float* ap = A + (size_t)(r0 + arow) * K + k0 + akq;
            float4 a0 = *(const float4*)ap, a1 = *(const float4*)(ap + 4);
            float av[8] = {a0.x, a0.y, a0.z, a0.w, a1.x, a1.y, a1.z, a1.w};
            s16x8 vh, vl;
#pragma unroll
            for (int i = 0; i < 8; ++i) { short hh, ll; splitf(av[i], hh, ll); vh[i] = hh; vl[i] = ll; }
            *(s16x8*)&Ah[arow][akq] = vh;
            *(s16x8*)&Al[arow][akq] = vl;
        }
        {
            const short* bph = BTh + (size_t)(c0 + bn) * K + k0 + bkq;
            const short* bpl = BTl + (size_t)(c0 + bn) * K + k0 + bkq;
            *(s16x8*)&Bh[bn][bkq]     = *(const s16x8*)bph;
            *(s16x8*)&Bh[bn][bkq + 8] = *(const s16x8*)(bph + 8);
            *(s16x8*)&Bl[bn][bkq]     = *(const s16x8*)bpl;
            *(s16x8*)&Bl[bn][bkq + 8] = *(const s16x8*)(bpl + 8);
        }
        __syncthreads();
        int kb = kh * 32 + g * 8;
        s16x8 fAh0 = *(s16x8*)&Ah[cl][kb],      fAl0 = *(s16x8*)&Al[cl][kb];
        s16x8 fAh1 = *(s16x8*)&Ah[16 + cl][kb], fAl1 = *(s16x8*)&Al[16 + cl][kb];
        s16x8 fBh0 = *(s16x8*)&Bh[n0w + cl][kb],      fBl0 = *(s16x8*)&Bl[n0w + cl][kb];
        s16x8 fBh1 = *(s16x8*)&Bh[n0w + 16 + cl][kb], fBl1 = *(s16x8*)&Bl[n0w + 16 + cl][kb];
        acc[0][0] = mfma16(fAh0, fBh0, acc[0][0]);
        acc[0][0] = mfma16(fAl0, fBh0, acc[0][0]);
        acc[0][0] = mfma16(fAh0, fBl0, acc[0][0]);
        acc[0][1] = mfma16(fAh0, fBh1, acc[0][1]);
        acc[0][1] = mfma16(fAl0, fBh1, acc[0][1]);
        acc[0][1] = mfma16(fAh0, fBl1, acc[0][1]);
        acc[1][0] = mfma16(fAh1, fBh0, acc[1][0]);
        acc[1][0] = mfma16(fAl1, fBh0, acc[1][0]);
        acc[1][0] = mfma16(fAh1, fBl0, acc[1][0]);
        acc[1][1] = mfma16(fAh1, fBh1, acc[1][1]);
        acc[1][1] = mfma16(fAl1, fBh1, acc[1][1]);
        acc[1][1] = mfma16(fAh1, fBl1, acc[1][1]);
    }

    __syncthreads();
    float* red = (float*)&Bh[0][0];
    if (kh == 1) {
        float* rp = red + (w & 1) * 1024 + lane * 16;
#pragma unroll
        for (int mt = 0; mt < 2; ++mt)
#pragma unroll
            for (int nt = 0; nt < 2; ++nt)
#pragma unroll
                for (int r = 0; r < 4; ++r) rp[(mt * 2 + nt) * 4 + r] = acc[mt][nt][r];
    }
    __syncthreads();
    if (kh == 0) {
        const float* rp = red + (w & 1) * 1024 + lane * 16;
#pragma unroll
        for (int mt = 0; mt < 2; ++mt)
#pragma unroll
            for (int nt = 0; nt < 2; ++nt) {
                int col = c0 + n0w + nt * 16 + cl;
                float bb = bias ? bias[col] : 0.f;
#pragma unroll
                for (int r = 0; r < 4; ++r) {
                    float v = acc[mt][nt][r] + rp[(mt * 2 + nt) * 4 + r] + bb;
                    if (relu) v = fmaxf(v, 0.f);
                    C[(size_t)(r0 + mt * 16 + g * 4 + r) * NC + col] = v;
                }
            }
    }
}

// ---------------- flash attention v6: lean-LDS (K+P only), Q/V direct-to-reg ----------------
// Grid (head, qblock 32, key-split). Block = 2 waves. LDS holds ONLY K (cross-wave staged,
// reg-prefetch double-buffered) and P (intra-wave transpose) + mask words: ~19.7 KB ->
// 8 blocks/CU -> 4 waves/SIMD. Q fragments load global->reg once (consume layout); V
// fragments load global->reg per tile from pre-transposed vth/vtl (L2-resident), issued
// right after the staging barrier so HBM/L2 latency hides under QK^T + softmax.
// Masked-only splits: p=exp(0)=1 garbage accumulates with m=-1e30; combine weight
// exp(m-M)=0 cancels it exactly. Every row attends itself, so global M is always real.

__global__ __launch_bounds__(128, 4) void k_attn(const short* __restrict__ qkh, const short* __restrict__ qkl,
                                                 const short* __restrict__ vth, const short* __restrict__ vtl,
                                                 const unsigned* __restrict__ mbits,
                                                 float* __restrict__ po, float* __restrict__ pml) {
    __shared__ short Kh[64][40], Kl[64][40];      // [key][dh]   10240 B
    __shared__ short Ph[32][72], Pl[32][72];      // [q][key]     9216 B (per-wave 16-row regions)
    __shared__ unsigned mwv[32][2];

    int h = blockIdx.x, q0 = blockIdx.y * 32, sp = blockIdx.z;
    int c_begin = sp * SPLEN_, c_end = c_begin + SPLEN_;
    int tid = threadIdx.x;
    int w = tid >> 6, lane = tid & 63;
    int g = lane >> 4, cl = lane & 15;
    int wq = w * 16;
    const float scale = 0.17677669529663687f;   // 1/sqrt(32)

    // Q fragments: direct global->reg, consume layout (row = wq+cl, dh chunk = g*8)
    s16x8 fQh = *(const s16x8*)(qkh + (size_t)(q0 + wq + cl) * 512 + h * DH_ + g * 8);
    s16x8 fQl = *(const s16x8*)(qkl + (size_t)(q0 + wq + cl) * 512 + h * DH_ + g * 8);

    // V fragment base rows (consume layout: row = h*32 + nt*16 + cl)
    const short* vh0 = vth + (size_t)(h * DH_ + cl) * S_;        // nt = 0
    const short* vh1 = vth + (size_t)(h * DH_ + 16 + cl) * S_;   // nt = 1
    const short* vl0 = vtl + (size_t)(h * DH_ + cl) * S_;
    const short* vl1 = vtl + (size_t)(h * DH_ + 16 + cl) * S_;

    // K staging (fixed per-thread addresses), reg-prefetch double-buffer
    int krow = tid & 63, kb0 = (tid >> 6) * 16;
    s16x8 rKh0, rKh1, rKl0, rKl1;
    {
        const short* ph = qkh + (size_t)(c_begin + krow) * 512 + 256 + h * DH_ + kb0;
        const short* pl = qkl + (size_t)(c_begin + krow) * 512 + 256 + h * DH_ + kb0;
        rKh0 = *(const s16x8*)ph; rKh1 = *(const s16x8*)(ph + 8);
        rKl0 = *(const s16x8*)pl; rKl1 = *(const s16x8*)(pl + 8);
    }

    float mrow[4], lrow[4];
#pragma unroll
    for (int r = 0; r < 4; ++r) { mrow[r] = -3.0e38f; lrow[r] = 0.f; }
    f32x4 accO[2] = {(f32x4){0.f,0.f,0.f,0.f}, (f32x4){0.f,0.f,0.f,0.f}};

    for (int c0 = c_begin; c0 < c_end; c0 += 64) {
        __syncthreads();   // prev tile's K reads done
        {   // K reg -> LDS
            *(s16x8*)&Kh[krow][kb0]     = rKh0;
            *(s16x8*)&Kh[krow][kb0 + 8] = rKh1;
            *(s16x8*)&Kl[krow][kb0]     = rKl0;
            *(s16x8*)&Kl[krow][kb0 + 8] = rKl1;
        }
        if (tid < 64) mwv[tid >> 1][tid & 1] = mbits[(size_t)(q0 + (tid >> 1)) * SW_ + (c0 >> 5) + (tid & 1)];

        // V fragments for THIS tile: issue now, consumed at PV (latency hides under QK^T+softmax)
        s16x8 fVh00 = *(const s16x8*)(vh0 + c0 + g * 8);
        s16x8 fVh01 = *(const s16x8*)(vh0 + c0 + 32 + g * 8);
        s16x8 fVh10 = *(const s16x8*)(vh1 + c0 + g * 8);
        s16x8 fVh11 = *(const s16x8*)(vh1 + c0 + 32 + g * 8);
        s16x8 fVl00 = *(const s16x8*)(vl0 + c0 + g * 8);
        s16x8 fVl01 = *(const s16x8*)(vl0 + c0 + 32 + g * 8);
        s16x8 fVl10 = *(const s16x8*)(vl1 + c0 + g * 8);
        s16x8 fVl11 = *(const s16x8*)(vl1 + c0 + 32 + g * 8);

        if (c0 + 64 < c_end) {   // prefetch next K tile into regs
            const short* ph = qkh + (size_t)(c0 + 64 + krow) * 512 + 256 + h * DH_ + kb0;
            const short* pl = qkl + (size_t)(c0 + 64 + krow) * 512 + 256 + h * DH_ + kb0;
            rKh0 = *(const s16x8*)ph; rKh1 = *(const s16x8*)(ph + 8);
            rKl0 = *(const s16x8*)pl; rKl1 = *(const s16x8*)(pl + 8);
        }
        __syncthreads();   // K staged

        // ---- QK^T: wave's 16 q-rows vs all 64 keys ----
        f32x4 sc[4];
#pragma unroll
        for (int nt2 = 0; nt2 < 4; ++nt2) {
            s16x8 fKh = *(s16x8*)&Kh[nt2 * 16 + cl][g * 8], fKl = *(s16x8*)&Kl[nt2 * 16 + cl][g * 8];
            f32x4 z = (f32x4){0.f, 0.f, 0.f, 0.f};
            z = mfma16(fQh, fKh, z);
            z = mfma16(fQl, fKh, z);
            z = mfma16(fQh, fKl, z);
            sc[nt2] = z;
        }

        float sv[4][4];
#pragma unroll
        for (int nt2 = 0; nt2 < 4; ++nt2) {
            int wi = nt2 >> 1;
            unsigned bit = 1u << (((nt2 & 1) << 4) + cl);
#pragma unroll
            for (int r = 0; r < 4; ++r)
                sv[nt2][r] = (mwv[wq + g * 4 + r][wi] & bit) ? -1.0e30f : sc[nt2][r] * scale;
        }

        float srw[4];
#pragma unroll
        for (int r = 0; r < 4; ++r) {
            float v = fmaxf(fmaxf(sv[0][r], sv[1][r]), fmaxf(sv[2][r], sv[3][r]));
            v = fmaxf(v, __shfl_xor(v, 1));
            v = fmaxf(v, __shfl_xor(v, 2));
            v = fmaxf(v, __shfl_xor(v, 4));
            v = fmaxf(v, __shfl_xor(v, 8));
            float mn = fmaxf(mrow[r], v);
            srw[r] = __expf(mrow[r] - mn);
            mrow[r] = mn;
            float psum = 0.f;
#pragma unroll
            for (int nt2 = 0; nt2 < 4; ++nt2) {
                float p = __expf(sv[nt2][r] - mn);
                psum += p;
                short ph = f2bf(p);
                Ph[wq + g * 4 + r][nt2 * 16 + cl] = ph;
                Pl[wq + g * 4 + r][nt2 * 16 + cl] = f2bf(p - bf2f(ph));
            }
            psum += __shfl_xor(psum, 1);
            psum += __shfl_xor(psum, 2);
            psum += __shfl_xor(psum, 4);
            psum += __shfl_xor(psum, 8);
            lrow[r] = lrow[r] * srw[r] + psum;
        }

        // ---- PV: reg V frags, LDS P frags (same-wave region) ----
#pragma unroll
        for (int nt = 0; nt < 2; ++nt)
#pragma unroll
            for (int r = 0; r < 4; ++r) accO[nt][r] *= srw[r];

        {
            s16x8 fPh0 = *(s16x8*)&Ph[wq + cl][g * 8];
            s16x8 fPl0 = *(s16x8*)&Pl[wq + cl][g * 8];
            accO[0] = mfma16(fPh0, fVh00, accO[0]);
            accO[0] = mfma16(fPl0, fVh00, accO[0]);
            accO[0] = mfma16(fPh0, fVl00, accO[0]);
            accO[1] = mfma16(fPh0, fVh10, accO[1]);
            accO[1] = mfma16(fPl0, fVh10, accO[1]);
            accO[1] = mfma16(fPh0, fVl10, accO[1]);
            s16x8 fPh1 = *(s16x8*)&Ph[wq + cl][32 + g * 8];
            s16x8 fPl1 = *(s16x8*)&Pl[wq + cl][32 + g * 8];
            accO[0] = mfma16(fPh1, fVh01, accO[0]);
            accO[0] = mfma16(fPl1, fVh01, accO[0]);
            accO[0] = mfma16(fPh1, fVl01, accO[0]);
            accO[1] = mfma16(fPh1, fVh11, accO[1]);
            accO[1] = mfma16(fPl1, fVh11, accO[1]);
            accO[1] = mfma16(fPh1, fVl11, accO[1]);
        }
    }

    // write unnormalized partial + (m, l)
#pragma unroll
    for (int nt = 0; nt < 2; ++nt)
#pragma unroll
        for (int r = 0; r < 4; ++r) {
            int row = q0 + wq + g * 4 + r;
            po[((size_t)sp * S_ + row) * D_ + h * DH_ + nt * 16 + cl] = accO[nt][r];
        }
    if (cl == 0) {
#pragma unroll
        for (int r = 0; r < 4; ++r) {
            int row = q0 + wq + g * 4 + r;
            size_t base = (((size_t)sp * S_ + row) * HEADS_ + h) * 2;
            pml[base] = mrow[r];
            pml[base + 1] = lrow[r];
        }
    }
}

// ---------------- flash split combine ----------------

__global__ __launch_bounds__(256) void k_acomb(const float* __restrict__ po, const float* __restrict__ pml,
                                               float* __restrict__ o) {
    int row = blockIdx.x, d = threadIdx.x, h = d >> 5;
    float m[NSPLIT_], l[NSPLIT_];
#pragma unroll
    for (int sp = 0; sp < NSPLIT_; ++sp) {
        size_t base = (((size_t)sp * S_ + row) * HEADS_ + h) * 2;
        m[sp] = pml[base];
        l[sp] = pml[base + 1];
    }
    float M = fmaxf(fmaxf(m[0], m[1]), fmaxf(m[2], m[3]));
    float L = 0.f, acc = 0.f;
#pragma unroll
    for (int sp = 0; sp < NSPLIT_; ++sp) {
        float wgt = __expf(m[sp] - M);
        L += l[sp] * wgt;
        acc += po[((size_t)sp * S_ + row) * D_ + d] * wgt;
    }
    o[(size_t)row * D_ + d] = acc / L;
}

// ---------------- residual add + LayerNorm ----------------

__global__ __launch_bounds__(256) void k_addln(float* __restrict__ x, const float* __restrict__ add,
                                               const float* __restrict__ gg, const float* __restrict__ bb) {
    int row = blockIdx.x, d = threadIdx.x;
    float val = x[row * D_ + d] + add[row * D_ + d];

    __shared__ float w4[4];
    __shared__ float bc[2];

    float ss = val;
    for (int o = 32; o; o >>= 1) ss += __shfl_down(ss, o, 64);
    if ((d & 63) == 0) w4[d >> 6] = ss;
    __syncthreads();
    if (d == 0) bc[0] = (w4[0] + w4[1] + w4[2] + w4[3]) * (1.f / D_);
    __syncthreads();
    float mu = bc[0];
    float c = val - mu;
    float vs = c * c;
    for (int o = 32; o; o >>= 1) vs += __shfl_down(vs, o, 64);
    __syncthreads();
    if ((d & 63) == 0) w4[d >> 6] = vs;
    __syncthreads();
    if (d == 0) bc[1] = (w4[0] + w4[1] + w4[2] + w4[3]) * (1.f / D_);
    __syncthreads();
    float var = bc[1];
    float rr = rsqrtf(var + 1e-6f);
    x[row * D_ + d] = c * rr * gg[d] + bb[d];
}

// ---------------- final projection ----------------

__global__ __launch_bounds__(256) void k_final(const float* __restrict__ x, const float* __restrict__ fcw,
                                               const float* __restrict__ fcb, const float* __restrict__ tnw,
                                               const float* __restrict__ tnb, float* __restrict__ out) {
    int row = blockIdx.x, d = threadIdx.x;
    float p = x[row * D_ + d] * fcw[d];
    for (int o = 32; o; o >>= 1) p += __shfl_down(p, o, 64);
    __shared__ float w4[4];
    if ((d & 63) == 0) w4[d >> 6] = p;
    __syncthreads();
    if (d == 0) {
        float s = w4[0] + w4[1] + w4[2] + w4[3];
        out[row] = (s + fcb[0]) * tnw[0] + tnb[0];
    }
}

// ---------------- launch ----------------

extern "C" void kernel_launch(void* const* d_in, const int* in_sizes, int n_in,
                              void* d_out, int out_size, void* d_ws, size_t ws_size,
                              hipStream_t stream) {
    const float* r_t   = (const float*)d_in[0];
    const float* H     = (const float*)d_in[1];
    const float* mask  = (const float*)d_in[2];
    const float* src   = (const float*)d_in[3];
    const float* tt    = (const float*)d_in[4];
    const float* Wq    = (const float*)d_in[5];
    const float* Wk    = (const float*)d_in[6];
    const float* Wv    = (const float*)d_in[7];
    const float* Wo    = (const float*)d_in[8];
    const float* W1    = (const float*)d_in[9];
    const float* b1    = (const float*)d_in[10];
    const float* W2    = (const float*)d_in[11];
    const float* b2    = (const float*)d_in[12];
    const float* ln1g  = (const float*)d_in[13];
    const float* ln1b  = (const float*)d_in[14];
    const float* ln2g  = (const float*)d_in[15];
    const float* ln2b  = (const float*)d_in[16];
    const float* fcw   = (const float*)d_in[17];
    const float* fcb   = (const float*)d_in[18];
    const float* tnw   = (const float*)d_in[19];
    const float* tnb   = (const float*)d_in[20];
    const int*   tptr  = (const int*)d_in[21];
    float* out = (float*)d_out;

    float* ws    = (float*)d_ws;
    float* x     = ws;                       // S*D
    float* qkv   = x    + S_ * D_;           // S*768
    float* ao    = qkv  + S_ * 768;          // S*D
    float* tmp   = ao   + S_ * D_;           // S*D
    float* h1    = tmp  + S_ * D_;           // S*4D
    float* nodes = h1   + S_ * 4 * D_;       // S
    unsigned* mbits = (unsigned*)(nodes + S_);             // S*SW words
    short* WqkvTh = (short*)(mbits + S_ * SW_);
    short* WqkvTl = WqkvTh + LAYERS_ * 768 * 256;
    short* WoTh   = WqkvTl + LAYERS_ * 768 * 256;
    short* WoTl   = WoTh   + LAYERS_ * 256 * 256;
    short* W1Th   = WoTl   + LAYERS_ * 256 * 256;
    short* W1Tl   = W1Th   + LAYERS_ * 1024 * 256;
    short* W2Th   = W1Tl   + LAYERS_ * 1024 * 256;
    short* W2Tl   = W2Th   + LAYERS_ * 256 * 1024;
    short* qkh    = W2Tl   + LAYERS_ * 256 * 1024;         // S*512
    short* qkl    = qkh    + S_ * 512;                     // S*512
    short* vth    = qkl    + S_ * 512;                     // 256*S
    short* vtl    = vth    + 256 * S_;                     // 256*S
    float* po     = (float*)(vtl + 256 * S_);              // NSPLIT*S*D
    float* pml    = po + (size_t)NSPLIT_ * S_ * D_;        // NSPLIT*S*HEADS*2

    k_absr<<<(N_ + 255) / 256, 256, 0, stream>>>(r_t, nodes);
    k_synd<<<M_, 256, 0, stream>>>(r_t, H, nodes);
    k_maskpack<<<(S_ * SW_ + 255) / 256, 256, 0, stream>>>(mask, mbits);
    k_embed<<<S_, 256, 0, stream>>>(src, tt, tptr, nodes, x);

    k_wsplit<<<dim3(8, 8, 6),  256, 0, stream>>>(Wq, WqkvTh,             WqkvTl,             256, 256,  65536, 196608);
    k_wsplit<<<dim3(8, 8, 6),  256, 0, stream>>>(Wk, WqkvTh + 256 * 256, WqkvTl + 256 * 256, 256, 256,  65536, 196608);
    k_wsplit<<<dim3(8, 8, 6),  256, 0, stream>>>(Wv, WqkvTh + 512 * 256, WqkvTl + 512 * 256, 256, 256,  65536, 196608);
    k_wsplit<<<dim3(8, 8, 6),  256, 0, stream>>>(Wo, WoTh, WoTl, 256, 256,  65536, 65536);
    k_wsplit<<<dim3(32, 8, 6), 256, 0, stream>>>(W1, W1Th, W1Tl, 256, 1024, 262144, 262144);
    k_wsplit<<<dim3(8, 32, 6), 256, 0, stream>>>(W2, W2Th, W2Tl, 1024, 256, 262144, 262144);

    for (int i = 0; i < LAYERS_; ++i) {
        k_mgemm<<<dim3(12, 72), 256, 0, stream>>>(x, WqkvTh + (size_t)i * 196608, WqkvTl + (size_t)i * 196608,
                                                  qkv, 256, 768, nullptr, 0);
        k_qksplit<<<576, 256, 0, stream>>>(qkv, qkh, qkl);
        k_vsplit<<<dim3(36, 8), 256, 0, stream>>>(qkv, vth, vtl);
        k_attn<<<dim3(HEADS_, S_ / 32, NSPLIT_), 128, 0, stream>>>(qkh, qkl, vth, vtl, mbits, po, pml);
        k_acomb<<<S_, 256, 0, stream>>>(po, pml, ao);
        k_mgemm<<<dim3(4, 72), 256, 0, stream>>>(ao, WoTh + (size_t)i * 65536, WoTl + (size_t)i * 65536,
                                                 tmp, 256, 256, nullptr, 0);
        k_addln<<<S_, 256, 0, stream>>>(x, tmp, ln1g + i * D_, ln1b + i * D_);
        k_mgemm<<<dim3(16, 72), 256, 0, stream>>>(x, W1Th + (size_t)i * 262144, W1Tl + (size_t)i * 262144,
                                                  h1, 256, 1024, b1 + i * 4 * D_, 1);
        k_mgemm<<<dim3(4, 72), 256, 0, stream>>>(h1, W2Th + (size_t)i * 262144, W2Tl + (size_t)i * 262144,
                                                 tmp, 1024, 256, b2 + i * D_, 0);
        k_addln<<<S_, 256, 0, stream>>>(x, tmp, ln2g + i * D_, ln2b + i * D_);
    }

    k_final<<<N_, 256, 0, stream>>>(x, fcw, fcb, tnw, tnb, out);
}

// Round 14
// 801.846 us; speedup vs baseline: 1.2624x; 1.2624x over previous
//
#include <hip/hip_runtime.h>
#include <math.h>

#define N_  1536
#define M_  768
#define D_  256
#define HEADS_ 8
#define DH_ 32
#define LAYERS_ 6
#define S_  2304
#define SW_ (S_/32)   // 72 mask words per row
#define NSPLIT_ 4
#define SPLEN_ (S_/NSPLIT_)   // 576 keys per split, 9 tiles of 64

typedef __attribute__((ext_vector_type(8))) short  s16x8;
typedef __attribute__((ext_vector_type(8))) __bf16 bf16x8;
typedef __attribute__((ext_vector_type(4))) float  f32x4;

static __device__ __forceinline__ f32x4 mfma16(s16x8 a, s16x8 b, f32x4 c) {
    return __builtin_amdgcn_mfma_f32_16x16x32_bf16(
        __builtin_bit_cast(bf16x8, a), __builtin_bit_cast(bf16x8, b), c, 0, 0, 0);
}

static __device__ __forceinline__ short f2bf(float f) {
    unsigned u = __builtin_bit_cast(unsigned, f);
    unsigned r = u + 0x7FFFu + ((u >> 16) & 1u);   // RNE to bf16
    return (short)(r >> 16);
}
static __device__ __forceinline__ float bf2f(short s) {
    unsigned u = ((unsigned)(unsigned short)s) << 16;
    return __builtin_bit_cast(float, u);
}
static __device__ __forceinline__ void splitf(float f, short& h, short& l) {
    h = f2bf(f);
    l = f2bf(f - bf2f(h));
}

// ---------------- prep kernels ----------------

__global__ __launch_bounds__(256) void k_absr(const float* __restrict__ r, float* __restrict__ nodes) {
    int i = blockIdx.x * 256 + threadIdx.x;
    if (i < N_) nodes[i] = fabsf(r[i]);
}

__global__ __launch_bounds__(256) void k_synd(const float* __restrict__ r, const float* __restrict__ H,
                                              float* __restrict__ nodes) {
    int row = blockIdx.x;
    int tid = threadIdx.x;
    float s = 0.f;
    for (int j = tid; j < N_; j += 256) {
        float b = (r[j] < 0.f) ? 1.f : 0.f;
        s += H[row * N_ + j] * b;
    }
    for (int o = 32; o; o >>= 1) s += __shfl_down(s, o, 64);
    __shared__ float w4[4];
    if ((tid & 63) == 0) w4[tid >> 6] = s;
    __syncthreads();
    if (tid == 0) {
        float t = w4[0] + w4[1] + w4[2] + w4[3];
        nodes[N_ + row] = fmodf(t, 2.0f);
    }
}

__global__ __launch_bounds__(256) void k_maskpack(const float* __restrict__ mask, unsigned* __restrict__ bits) {
    int w = blockIdx.x * 256 + threadIdx.x;
    if (w >= S_ * SW_) return;
    int row = w / SW_, c0 = (w % SW_) * 32;
    unsigned b = 0;
    const float* mrow = mask + (size_t)row * S_ + c0;
    for (int j = 0; j < 32; ++j)
        if (mrow[j] != 0.f) b |= (1u << j);
    bits[w] = b;
}

__global__ __launch_bounds__(256) void k_embed(const float* __restrict__ src, const float* __restrict__ tt,
                                               const int* __restrict__ tptr, const float* __restrict__ nodes,
                                               float* __restrict__ x) {
    int s = blockIdx.x, d = threadIdx.x;
    int t = tptr[0];
    x[s * D_ + d] = src[s * D_ + d] * nodes[s] * tt[t * D_ + d];
}

// ---------------- weight transpose + bf16 hi/lo split ----------------

__global__ __launch_bounds__(256) void k_wsplit(const float* __restrict__ W, short* __restrict__ oh,
                                                short* __restrict__ ol, int K, int NC,
                                                long in_ls, long out_ls) {
    __shared__ float T[32][33];
    int z = blockIdx.z;
    const float* Wz = W + (size_t)z * in_ls;
    short* ohz = oh + (size_t)z * out_ls;
    short* olz = ol + (size_t)z * out_ls;
    int n0 = blockIdx.x * 32, k0 = blockIdx.y * 32;
    int t = threadIdx.x;
    int r = t >> 3, c4 = (t & 7) * 4;
    float4 v = *(const float4*)(Wz + (size_t)(k0 + r) * NC + n0 + c4);
    T[r][c4 + 0] = v.x; T[r][c4 + 1] = v.y; T[r][c4 + 2] = v.z; T[r][c4 + 3] = v.w;
    __syncthreads();
    int n = t >> 3, k4 = (t & 7) * 4;
#pragma unroll
    for (int i = 0; i < 4; ++i) {
        float f = T[k4 + i][n];
        short hh, ll; splitf(f, hh, ll);
        ohz[(size_t)(n0 + n) * K + k0 + k4 + i] = hh;
        olz[(size_t)(n0 + n) * K + k0 + k4 + i] = ll;
    }
}

// ---------------- QKV pre-split kernels (once per layer) ----------------

__global__ __launch_bounds__(256) void k_qksplit(const float* __restrict__ qkv, short* __restrict__ qkh,
                                                 short* __restrict__ qkl) {
    int u = (blockIdx.x * 256 + threadIdx.x) * 8;
    int s = u >> 9, c = u & 511;
    const float* p = qkv + (size_t)s * 768 + c;
    float4 a = *(const float4*)p, b = *(const float4*)(p + 4);
    float v[8] = {a.x, a.y, a.z, a.w, b.x, b.y, b.z, b.w};
    s16x8 vh, vl;
#pragma unroll
    for (int i = 0; i < 8; ++i) { short hh, ll; splitf(v[i], hh, ll); vh[i] = hh; vl[i] = ll; }
    *(s16x8*)(qkh + u) = vh;
    *(s16x8*)(qkl + u) = vl;
}

__global__ __launch_bounds__(256) void k_vsplit(const float* __restrict__ qkv, short* __restrict__ vth,
                                                short* __restrict__ vtl) {
    __shared__ short Th[32][72], Tl[32][72];
    int s0 = blockIdx.x * 64, h = blockIdx.y;
    int t = threadIdx.x;
    {
        int row = t >> 2, c8 = (t & 3) * 8;
        const float* p = qkv + (size_t)(s0 + row) * 768 + 512 + h * DH_ + c8;
        float4 a = *(const float4*)p, b = *(const float4*)(p + 4);
        float v[8] = {a.x, a.y, a.z, a.w, b.x, b.y, b.z, b.w};
#pragma unroll
        for (int i = 0; i < 8; ++i) { short hh, ll; splitf(v[i], hh, ll); Th[c8 + i][row] = hh; Tl[c8 + i][row] = ll; }
    }
    __syncthreads();
    {
        int dh = t >> 3, seg = (t & 7) * 8;
        *(s16x8*)(vth + (size_t)(h * DH_ + dh) * S_ + s0 + seg) = *(s16x8*)&Th[dh][seg];
        *(s16x8*)(vtl + (size_t)(h * DH_ + dh) * S_ + s0 + seg) = *(s16x8*)&Tl[dh][seg];
    }
}

// ---------------- MFMA GEMM (unchanged) ----------------

__global__ __launch_bounds__(256) void k_mgemm(const float* __restrict__ A, const short* __restrict__ BTh,
                                               const short* __restrict__ BTl, float* __restrict__ C,
                                               int K, int NC, const float* __restrict__ bias, int relu) {
    __shared__ short Ah[32][72], Al[32][72];
    __shared__ short Bh[64][72], Bl[64][72];
    int tid = threadIdx.x;
    int w = tid >> 6, lane = tid & 63;
    int n0w = (w & 1) * 32, kh = w >> 1;
    int r0 = blockIdx.y * 32, c0 = blockIdx.x * 64;
    int g = lane >> 4, cl = lane & 15;

    f32x4 acc[2][2];
#pragma unroll
    for (int mt = 0; mt < 2; ++mt)
#pragma unroll
        for (int nt = 0; nt < 2; ++nt) acc[mt][nt] = (f32x4){0.f, 0.f, 0.f, 0.f};

    int arow = tid >> 3, akq = (tid & 7) * 8;
    int bn = tid >> 2, bkq = (tid & 3) * 16;

    for (int k0 = 0; k0 < K; k0 += 64) {
        __syncthreads();
        {
            const float* ap = A + (size_t)(r0 + arow) * K + k0 + akq;
            float4 a0 = *(const float4*)ap, a1 = *(const float4*)(ap + 4);
            float av[8] = {a0.x, a0.y, a0.z, a0.w, a1.x, a1.y, a1.z, a1.w};
            s16x8 vh, vl;
#pragma unroll
            for (int i = 0; i < 8; ++i) { short hh, ll; splitf(av[i], hh, ll); vh[i] = hh; vl[i] = ll; }
            *(s16x8*)&Ah[arow][akq] = vh;
            *(s16x8*)&Al[arow][akq] = vl;
        }
        {
            const short* bph = BTh + (size_t)(c0 + bn) * K + k0 + bkq;
            const short* bpl = BTl + (size_t)(c0 + bn) * K + k0 + bkq;
            *(s16x8*)&Bh[bn][bkq]     = *(const s16x8*)bph;
            *(s16x8*)&Bh[bn][bkq + 8] = *(const s16x8*)(bph + 8);
            *(s16x8*)&Bl[bn][bkq]     = *(const s16x8*)bpl;
            *(s16x8*)&Bl[bn][bkq + 8] = *(const s16x8*)(bpl + 8);
        }
        __syncthreads();
        int kb = kh * 32 + g * 8;
        s16x8 fAh0 = *(s16x8*)&Ah[cl][kb],      fAl0 = *(s16x8*)&Al[cl][kb];
        s16x8 fAh1 = *(s16x8*)&Ah[16 + cl][kb], fAl1 = *(s16x8*)&Al[16 + cl][kb];
        s16x8 fBh0 = *(s16x8*)&Bh[n0w + cl][kb],      fBl0 = *(s16x8*)&Bl[n0w + cl][kb];
        s16x8 fBh1 = *(s16x8*)&Bh[n0w + 16 + cl][kb], fBl1 = *(s16x8*)&Bl[n0w + 16 + cl][kb];
        acc[0][0] = mfma16(fAh0, fBh0, acc[0][0]);
        acc[0][0] = mfma16(fAl0, fBh0, acc[0][0]);
        acc[0][0] = mfma16(fAh0, fBl0, acc[0][0]);
        acc[0][1] = mfma16(fAh0, fBh1, acc[0][1]);
        acc[0][1] = mfma16(fAl0, fBh1, acc[0][1]);
        acc[0][1] = mfma16(fAh0, fBl1, acc[0][1]);
        acc[1][0] = mfma16(fAh1, fBh0, acc[1][0]);
        acc[1][0] = mfma16(fAl1, fBh0, acc[1][0]);
        acc[1][0] = mfma16(fAh1, fBl0, acc[1][0]);
        acc[1][1] = mfma16(fAh1, fBh1, acc[1][1]);
        acc[1][1] = mfma16(fAl1, fBh1, acc[1][1]);
        acc[1][1] = mfma16(fAh1, fBl1, acc[1][1]);
    }

    __syncthreads();
    float* red = (float*)&Bh[0][0];
    if (kh == 1) {
        float* rp = red + (w & 1) * 1024 + lane * 16;
#pragma unroll
        for (int mt = 0; mt < 2; ++mt)
#pragma unroll
            for (int nt = 0; nt < 2; ++nt)
#pragma unroll
                for (int r = 0; r < 4; ++r) rp[(mt * 2 + nt) * 4 + r] = acc[mt][nt][r];
    }
    __syncthreads();
    if (kh == 0) {
        const float* rp = red + (w & 1) * 1024 + lane * 16;
#pragma unroll
        for (int mt = 0; mt < 2; ++mt)
#pragma unroll
            for (int nt = 0; nt < 2; ++nt) {
                int col = c0 + n0w + nt * 16 + cl;
                float bb = bias ? bias[col] : 0.f;
#pragma unroll
                for (int r = 0; r < 4; ++r) {
                    float v = acc[mt][nt][r] + rp[(mt * 2 + nt) * 4 + r] + bb;
                    if (relu) v = fmaxf(v, 0.f);
                    C[(size_t)(r0 + mt * 16 + g * 4 + r) * NC + col] = v;
                }
            }
    }
}

// ---------------- flash attention v7: swapped QK^T, per-lane scalar softmax ----------------
// REVERT of v6's per-tile V/Q direct-reg loads (uncoalesced, +62% hbm_bytes, 75->92us) back
// to v5's coalesced K+V reg-prefetch LDS staging. NEW: QK^T computed as mfma(K, Q) so
// C[key = g*4+r][q = cl] -- each lane holds ALL 64 keys of ONE q-row (16 regs over nt2,r).
// Softmax row-reduce: 15 in-reg ops + 2 shfl_xor (g-groups) vs v5's 32 shfl/tile. m,l are
// per-lane scalars; rescale factor broadcast to PV rows via 32-float LDS (1 write + 1
// ds_read_b128, wave-local so no barrier). Q is a one-time global->reg load (B-operand
// layout), amortized over 9 tiles. LDS ~29 KB -> 5 blocks/CU.
// Masked-only splits: p=exp(0)=1 garbage accumulates with m=-1e30; combine weight
// exp(m-M)=0 cancels it exactly. Every row attends itself, so global M is always real.

__global__ __launch_bounds__(128) void k_attn(const short* __restrict__ qkh, const short* __restrict__ qkl,
                                              const short* __restrict__ vth, const short* __restrict__ vtl,
                                              const unsigned* __restrict__ mbits,
                                              float* __restrict__ po, float* __restrict__ pml) {
    __shared__ short Kh[64][40], Kl[64][40];      // [key][dh]   10240 B
    __shared__ short Vh[32][72], Vl[32][72];      // [dh][key]    9216 B
    __shared__ short Ph[32][72], Pl[32][72];      // [q][key]     9216 B (per-wave 16-row regions)
    __shared__ unsigned mwv[32][2];
    __shared__ float sfac[32];                    // per-q rescale broadcast

    int h = blockIdx.x, q0 = blockIdx.y * 32, sp = blockIdx.z;
    int c_begin = sp * SPLEN_, c_end = c_begin + SPLEN_;
    int tid = threadIdx.x;
    int w = tid >> 6, lane = tid & 63;
    int g = lane >> 4, cl = lane & 15;
    int wq = w * 16;
    const float scale = 0.17677669529663687f;   // 1/sqrt(32)

    // Q fragments (B-operand): lane (g,cl) holds Q[q = wq+cl][dh chunk g*8] -- one-time load
    s16x8 fQh = *(const s16x8*)(qkh + (size_t)(q0 + wq + cl) * 512 + h * DH_ + g * 8);
    s16x8 fQl = *(const s16x8*)(qkl + (size_t)(q0 + wq + cl) * 512 + h * DH_ + g * 8);

    // K/V staging (fixed per-thread addresses), reg-prefetch double-buffer (coalesced)
    int krow = tid & 63, kb0 = (tid >> 6) * 16;
    int vdh = tid >> 2, vb0 = (tid & 3) * 16;
    s16x8 rKh0, rKh1, rKl0, rKl1, rVh0, rVh1, rVl0, rVl1;
    {
        const short* ph = qkh + (size_t)(c_begin + krow) * 512 + 256 + h * DH_ + kb0;
        const short* pl = qkl + (size_t)(c_begin + krow) * 512 + 256 + h * DH_ + kb0;
        rKh0 = *(const s16x8*)ph; rKh1 = *(const s16x8*)(ph + 8);
        rKl0 = *(const s16x8*)pl; rKl1 = *(const s16x8*)(pl + 8);
        const short* vh = vth + (size_t)(h * DH_ + vdh) * S_ + c_begin + vb0;
        const short* vl = vtl + (size_t)(h * DH_ + vdh) * S_ + c_begin + vb0;
        rVh0 = *(const s16x8*)vh; rVh1 = *(const s16x8*)(vh + 8);
        rVl0 = *(const s16x8*)vl; rVl1 = *(const s16x8*)(vl + 8);
    }

    float m = -3.0e38f, l = 0.f;                  // per-lane scalars, q = wq+cl
    f32x4 accO[2] = {(f32x4){0.f,0.f,0.f,0.f}, (f32x4){0.f,0.f,0.f,0.f}};

    for (int c0 = c_begin; c0 < c_end; c0 += 64) {
        __syncthreads();   // prev tile's K/V reads done
        {   // reg -> LDS
            *(s16x8*)&Kh[krow][kb0]     = rKh0;
            *(s16x8*)&Kh[krow][kb0 + 8] = rKh1;
            *(s16x8*)&Kl[krow][kb0]     = rKl0;
            *(s16x8*)&Kl[krow][kb0 + 8] = rKl1;
            *(s16x8*)&Vh[vdh][vb0]      = rVh0;
            *(s16x8*)&Vh[vdh][vb0 + 8]  = rVh1;
            *(s16x8*)&Vl[vdh][vb0]      = rVl0;
            *(s16x8*)&Vl[vdh][vb0 + 8]  = rVl1;
        }
        if (tid < 64) mwv[tid >> 1][tid & 1] = mbits[(size_t)(q0 + (tid >> 1)) * SW_ + (c0 >> 5) + (tid & 1)];
        if (c0 + 64 < c_end) {   // prefetch next tile into regs (overlaps compute)
            const short* ph = qkh + (size_t)(c0 + 64 + krow) * 512 + 256 + h * DH_ + kb0;
            const short* pl = qkl + (size_t)(c0 + 64 + krow) * 512 + 256 + h * DH_ + kb0;
            rKh0 = *(const s16x8*)ph; rKh1 = *(const s16x8*)(ph + 8);
            rKl0 = *(const s16x8*)pl; rKl1 = *(const s16x8*)(pl + 8);
            const short* vh = vth + (size_t)(h * DH_ + vdh) * S_ + c0 + 64 + vb0;
            const short* vl = vtl + (size_t)(h * DH_ + vdh) * S_ + c0 + 64 + vb0;
            rVh0 = *(const s16x8*)vh; rVh1 = *(const s16x8*)(vh + 8);
            rVl0 = *(const s16x8*)vl; rVl1 = *(const s16x8*)(vl + 8);
        }
        __syncthreads();   // staged

        // mask words for this lane's q-row (keys c0..c0+63)
        unsigned mw0 = mwv[wq + cl][0], mw1 = mwv[wq + cl][1];

        // ---- QK^T swapped: C[key = g*4+r][q = cl]; lane holds 16 scores for its q-row ----
        f32x4 sc[4];
#pragma unroll
        for (int nt2 = 0; nt2 < 4; ++nt2) {
            s16x8 fKh = *(s16x8*)&Kh[nt2 * 16 + cl][g * 8], fKl = *(s16x8*)&Kl[nt2 * 16 + cl][g * 8];
            f32x4 z = (f32x4){0.f, 0.f, 0.f, 0.f};
            z = mfma16(fKh, fQh, z);
            z = mfma16(fKl, fQh, z);
            z = mfma16(fKh, fQl, z);
            sc[nt2] = z;
        }

        float sv[4][4];
#pragma unroll
        for (int nt2 = 0; nt2 < 4; ++nt2) {
            unsigned wsel = (nt2 & 2) ? mw1 : mw0;
#pragma unroll
            for (int r = 0; r < 4; ++r) {
                int bitpos = ((nt2 & 1) << 4) + (g << 2) + r;
                sv[nt2][r] = ((wsel >> bitpos) & 1u) ? -1.0e30f : sc[nt2][r] * scale;
            }
        }

        // ---- per-lane scalar online softmax (reduce 16 regs + 2 shfl over g) ----
        float tmax = sv[0][0];
#pragma unroll
        for (int nt2 = 0; nt2 < 4; ++nt2)
#pragma unroll
            for (int r = 0; r < 4; ++r) tmax = fmaxf(tmax, sv[nt2][r]);
        tmax = fmaxf(tmax, __shfl_xor(tmax, 16));
        tmax = fmaxf(tmax, __shfl_xor(tmax, 32));
        float mn = fmaxf(m, tmax);
        float sf = __expf(m - mn);
        m = mn;
        float psum = 0.f;
#pragma unroll
        for (int nt2 = 0; nt2 < 4; ++nt2)
#pragma unroll
            for (int r = 0; r < 4; ++r) {
                float p = __expf(sv[nt2][r] - mn);
                psum += p;
                short ph = f2bf(p);
                Ph[wq + cl][nt2 * 16 + (g << 2) + r] = ph;
                Pl[wq + cl][nt2 * 16 + (g << 2) + r] = f2bf(p - bf2f(ph));
            }
        psum += __shfl_xor(psum, 16);
        psum += __shfl_xor(psum, 32);
        l = l * sf + psum;

        // broadcast rescale factors to PV row owners (wave-local LDS; DS ops in-order per wave)
        if (g == 0) sfac[wq + cl] = sf;
        float4 sf4 = *(float4*)&sfac[wq + (g << 2)];
#pragma unroll
        for (int nt = 0; nt < 2; ++nt) {
            accO[nt][0] *= sf4.x; accO[nt][1] *= sf4.y;
            accO[nt][2] *= sf4.z; accO[nt][3] *= sf4.w;
        }

        // ---- PV: A = P rows (q), B = V cols (dh); C[q = g*4+r][dh = cl] ----
#pragma unroll
        for (int kc = 0; kc < 2; ++kc) {
            s16x8 fPh = *(s16x8*)&Ph[wq + cl][kc * 32 + g * 8];
            s16x8 fPl = *(s16x8*)&Pl[wq + cl][kc * 32 + g * 8];
#pragma unroll
            for (int nt = 0; nt < 2; ++nt) {
                s16x8 fVh = *(s16x8*)&Vh[nt * 16 + cl][kc * 32 + g * 8];
                s16x8 fVl = *(s16x8*)&Vl[nt * 16 + cl][kc * 32 + g * 8];
                accO[nt] = mfma16(fPh, fVh, accO[nt]);
                accO[nt] = mfma16(fPl, fVh, accO[nt]);
                accO[nt] = mfma16(fPh, fVl, accO[nt]);
            }
        }
    }

    // write unnormalized partial + (m, l)
#pragma unroll
    for (int nt = 0; nt < 2; ++nt)
#pragma unroll
        for (int r = 0; r < 4; ++r) {
            int row = q0 + wq + g * 4 + r;
            po[((size_t)sp * S_ + row) * D_ + h * DH_ + nt * 16 + cl] = accO[nt][r];
        }
    if (g == 0) {
        int row = q0 + wq + cl;
        size_t base = (((size_t)sp * S_ + row) * HEADS_ + h) * 2;
        pml[base] = m;
        pml[base + 1] = l;
    }
}

// ---------------- flash split combine ----------------

__global__ __launch_bounds__(256) void k_acomb(const float* __restrict__ po, const float* __restrict__ pml,
                                               float* __restrict__ o) {
    int row = blockIdx.x, d = threadIdx.x, h = d >> 5;
    float m[NSPLIT_], l[NSPLIT_];
#pragma unroll
    for (int sp = 0; sp < NSPLIT_; ++sp) {
        size_t base = (((size_t)sp * S_ + row) * HEADS_ + h) * 2;
        m[sp] = pml[base];
        l[sp] = pml[base + 1];
    }
    float M = fmaxf(fmaxf(m[0], m[1]), fmaxf(m[2], m[3]));
    float L = 0.f, acc = 0.f;
#pragma unroll
    for (int sp = 0; sp < NSPLIT_; ++sp) {
        float wgt = __expf(m[sp] - M);
        L += l[sp] * wgt;
        acc += po[((size_t)sp * S_ + row) * D_ + d] * wgt;
    }
    o[(size_t)row * D_ + d] = acc / L;
}

// ---------------- residual add + LayerNorm ----------------

__global__ __launch_bounds__(256) void k_addln(float* __restrict__ x, const float* __restrict__ add,
                                               const float* __restrict__ gg, const float* __restrict__ bb) {
    int row = blockIdx.x, d = threadIdx.x;
    float val = x[row * D_ + d] + add[row * D_ + d];

    __shared__ float w4[4];
    __shared__ float bc[2];

    float ss = val;
    for (int o = 32; o; o >>= 1) ss += __shfl_down(ss, o, 64);
    if ((d & 63) == 0) w4[d >> 6] = ss;
    __syncthreads();
    if (d == 0) bc[0] = (w4[0] + w4[1] + w4[2] + w4[3]) * (1.f / D_);
    __syncthreads();
    float mu = bc[0];
    float c = val - mu;
    float vs = c * c;
    for (int o = 32; o; o >>= 1) vs += __shfl_down(vs, o, 64);
    __syncthreads();
    if ((d & 63) == 0) w4[d >> 6] = vs;
    __syncthreads();
    if (d == 0) bc[1] = (w4[0] + w4[1] + w4[2] + w4[3]) * (1.f / D_);
    __syncthreads();
    float var = bc[1];
    float rr = rsqrtf(var + 1e-6f);
    x[row * D_ + d] = c * rr * gg[d] + bb[d];
}

// ---------------- final projection ----------------

__global__ __launch_bounds__(256) void k_final(const float* __restrict__ x, const float* __restrict__ fcw,
                                               const float* __restrict__ fcb, const float* __restrict__ tnw,
                                               const float* __restrict__ tnb, float* __restrict__ out) {
    int row = blockIdx.x, d = threadIdx.x;
    float p = x[row * D_ + d] * fcw[d];
    for (int o = 32; o; o >>= 1) p += __shfl_down(p, o, 64);
    __shared__ float w4[4];
    if ((d & 63) == 0) w4[d >> 6] = p;
    __syncthreads();
    if (d == 0) {
        float s = w4[0] + w4[1] + w4[2] + w4[3];
        out[row] = (s + fcb[0]) * tnw[0] + tnb[0];
    }
}

// ---------------- launch ----------------

extern "C" void kernel_launch(void* const* d_in, const int* in_sizes, int n_in,
                              void* d_out, int out_size, void* d_ws, size_t ws_size,
                              hipStream_t stream) {
    const float* r_t   = (const float*)d_in[0];
    const float* H     = (const float*)d_in[1];
    const float* mask  = (const float*)d_in[2];
    const float* src   = (const float*)d_in[3];
    const float* tt    = (const float*)d_in[4];
    const float* Wq    = (const float*)d_in[5];
    const float* Wk    = (const float*)d_in[6];
    const float* Wv    = (const float*)d_in[7];
    const float* Wo    = (const float*)d_in[8];
    const float* W1    = (const float*)d_in[9];
    const float* b1    = (const float*)d_in[10];
    const float* W2    = (const float*)d_in[11];
    const float* b2    = (const float*)d_in[12];
    const float* ln1g  = (const float*)d_in[13];
    const float* ln1b  = (const float*)d_in[14];
    const float* ln2g  = (const float*)d_in[15];
    const float* ln2b  = (const float*)d_in[16];
    const float* fcw   = (const float*)d_in[17];
    const float* fcb   = (const float*)d_in[18];
    const float* tnw   = (const float*)d_in[19];
    const float* tnb   = (const float*)d_in[20];
    const int*   tptr  = (const int*)d_in[21];
    float* out = (float*)d_out;

    float* ws    = (float*)d_ws;
    float* x     = ws;                       // S*D
    float* qkv   = x    + S_ * D_;           // S*768
    float* ao    = qkv  + S_ * 768;          // S*D
    float* tmp   = ao   + S_ * D_;           // S*D
    float* h1    = tmp  + S_ * D_;           // S*4D
    float* nodes = h1   + S_ * 4 * D_;       // S
    unsigned* mbits = (unsigned*)(nodes + S_);             // S*SW words
    short* WqkvTh = (short*)(mbits + S_ * SW_);
    short* WqkvTl = WqkvTh + LAYERS_ * 768 * 256;
    short* WoTh   = WqkvTl + LAYERS_ * 768 * 256;
    short* WoTl   = WoTh   + LAYERS_ * 256 * 256;
    short* W1Th   = WoTl   + LAYERS_ * 256 * 256;
    short* W1Tl   = W1Th   + LAYERS_ * 1024 * 256;
    short* W2Th   = W1Tl   + LAYERS_ * 1024 * 256;
    short* W2Tl   = W2Th   + LAYERS_ * 256 * 1024;
    short* qkh    = W2Tl   + LAYERS_ * 256 * 1024;         // S*512
    short* qkl    = qkh    + S_ * 512;                     // S*512
    short* vth    = qkl    + S_ * 512;                     // 256*S
    short* vtl    = vth    + 256 * S_;                     // 256*S
    float* po     = (float*)(vtl + 256 * S_);              // NSPLIT*S*D
    float* pml    = po + (size_t)NSPLIT_ * S_ * D_;        // NSPLIT*S*HEADS*2

    k_absr<<<(N_ + 255) / 256, 256, 0, stream>>>(r_t, nodes);
    k_synd<<<M_, 256, 0, stream>>>(r_t, H, nodes);
    k_maskpack<<<(S_ * SW_ + 255) / 256, 256, 0, stream>>>(mask, mbits);
    k_embed<<<S_, 256, 0, stream>>>(src, tt, tptr, nodes, x);

    k_wsplit<<<dim3(8, 8, 6),  256, 0, stream>>>(Wq, WqkvTh,             WqkvTl,             256, 256,  65536, 196608);
    k_wsplit<<<dim3(8, 8, 6),  256, 0, stream>>>(Wk, WqkvTh + 256 * 256, WqkvTl + 256 * 256, 256, 256,  65536, 196608);
    k_wsplit<<<dim3(8, 8, 6),  256, 0, stream>>>(Wv, WqkvTh + 512 * 256, WqkvTl + 512 * 256, 256, 256,  65536, 196608);
    k_wsplit<<<dim3(8, 8, 6),  256, 0, stream>>>(Wo, WoTh, WoTl, 256, 256,  65536, 65536);
    k_wsplit<<<dim3(32, 8, 6), 256, 0, stream>>>(W1, W1Th, W1Tl, 256, 1024, 262144, 262144);
    k_wsplit<<<dim3(8, 32, 6), 256, 0, stream>>>(W2, W2Th, W2Tl, 1024, 256, 262144, 262144);

    for (int i = 0; i < LAYERS_; ++i) {
        k_mgemm<<<dim3(12, 72), 256, 0, stream>>>(x, WqkvTh + (size_t)i * 196608, WqkvTl + (size_t)i * 196608,
                                                  qkv, 256, 768, nullptr, 0);
        k_qksplit<<<576, 256, 0, stream>>>(qkv, qkh, qkl);
        k_vsplit<<<dim3(36, 8), 256, 0, stream>>>(qkv, vth, vtl);
        k_attn<<<dim3(HEADS_, S_ / 32, NSPLIT_), 128, 0, stream>>>(qkh, qkl, vth, vtl, mbits, po, pml);
        k_acomb<<<S_, 256, 0, stream>>>(po, pml, ao);
        k_mgemm<<<dim3(4, 72), 256, 0, stream>>>(ao, WoTh + (size_t)i * 65536, WoTl + (size_t)i * 65536,
                                                 tmp, 256, 256, nullptr, 0);
        k_addln<<<S_, 256, 0, stream>>>(x, tmp, ln1g + i * D_, ln1b + i * D_);
        k_mgemm<<<dim3(16, 72), 256, 0, stream>>>(x, W1Th + (size_t)i * 262144, W1Tl + (size_t)i * 262144,
                                                  h1, 256, 1024, b1 + i * 4 * D_, 1);
        k_mgemm<<<dim3(4, 72), 256, 0, stream>>>(h1, W2Th + (size_t)i * 262144, W2Tl + (size_t)i * 262144,
                                                 tmp, 1024, 256, b2 + i * D_, 0);
        k_addln<<<S_, 256, 0, stream>>>(x, tmp, ln2g + i * D_, ln2b + i * D_);
    }

    k_final<<<N_, 256, 0, stream>>>(x, fcw, fcb, tnw, tnb, out);
}